// Round 1
// baseline (2277.248 us; speedup 1.0000x reference)
//
#include <hip/hip_runtime.h>
#include <math.h>

#define NT 4096
#define DM 1024
#define DF 2048
#define NEXP 16

typedef __attribute__((ext_vector_type(8))) short bf16x8;
typedef __attribute__((ext_vector_type(4))) float f32x4;

__device__ __forceinline__ unsigned short f2bf(float f) {
  unsigned int u = __builtin_bit_cast(unsigned int, f);
  u += 0x7fffu + ((u >> 16) & 1u);
  return (unsigned short)(u >> 16);
}

__device__ __forceinline__ void softmax4(float* v) {
  float m = fmaxf(fmaxf(v[0], v[1]), fmaxf(v[2], v[3]));
  float s = 0.f;
#pragma unroll
  for (int j = 0; j < 4; ++j) { v[j] = expf(v[j] - m); s += v[j]; }
  float inv = 1.f / s;
#pragma unroll
  for (int j = 0; j < 4; ++j) v[j] *= inv;
}

// One wave per token: 20 dot-products (4 group + 16 expert logits), then scalar router.
__global__ __launch_bounds__(64) void router_kernel(
    const float* __restrict__ x, const float* __restrict__ Wg,
    const float* __restrict__ We, int* __restrict__ counts,
    int* __restrict__ lists, float* __restrict__ wl) {
  int n = blockIdx.x;
  int lane = threadIdx.x;
  float acc[20];
#pragma unroll
  for (int j = 0; j < 20; ++j) acc[j] = 0.f;
  const float* xr = x + (size_t)n * DM;
  for (int c = lane; c < DM; c += 64) {
    float xv = xr[c];
    const float* wgr = Wg + c * 4;
#pragma unroll
    for (int j = 0; j < 4; ++j) acc[j] += xv * wgr[j];
    const float* wer = We + c * 16;
#pragma unroll
    for (int j = 0; j < 16; ++j) acc[4 + j] += xv * wer[j];
  }
#pragma unroll
  for (int j = 0; j < 20; ++j) {
    float v = acc[j];
    for (int s = 32; s; s >>= 1) v += __shfl_xor(v, s, 64);
    acc[j] = v;
  }
  if (lane == 0) {
    float gp[4];
#pragma unroll
    for (int g = 0; g < 4; ++g) gp[g] = acc[g];
    softmax4(gp);
    float ep[16];
#pragma unroll
    for (int g = 0; g < 4; ++g) {
      float t[4];
#pragma unroll
      for (int i = 0; i < 4; ++i) t[i] = acc[4 + g * 4 + i];
      softmax4(t);
#pragma unroll
      for (int i = 0; i < 4; ++i) ep[g * 4 + i] = t[i];
    }
    float fp[16];
    bool valid[16];
    int nsel = 0;
#pragma unroll
    for (int g = 0; g < 4; ++g) {
      bool gm = gp[g] >= 0.25f;
#pragma unroll
      for (int i = 0; i < 4; ++i) {
        int e = g * 4 + i;
        bool em = ep[e] >= 0.25f;
        valid[e] = gm && em;
        fp[e] = gp[g] * ep[e];
        nsel += valid[e] ? 1 : 0;
      }
    }
    // top-2 (ties -> lower index, matches lax.top_k)
    int m1 = 0; float v1 = -1.f;
#pragma unroll
    for (int e = 0; e < 16; ++e) if (fp[e] > v1) { v1 = fp[e]; m1 = e; }
    int m2 = -1; float v2 = -2.f;
#pragma unroll
    for (int e = 0; e < 16; ++e) if (e != m1 && fp[e] > v2) { v2 = fp[e]; m2 = e; }
    bool use_topk = nsel < 2;
    float sel[16]; float s = 0.f;
#pragma unroll
    for (int e = 0; e < 16; ++e) {
      bool msk = use_topk ? (e == m1 || e == m2) : valid[e];
      sel[e] = msk ? fp[e] : 0.f;
      s += sel[e];
      valid[e] = msk;  // reuse as final mask
    }
    float inv = 1.f / fmaxf(s, 1e-9f);
#pragma unroll
    for (int e = 0; e < 16; ++e) {
      if (valid[e]) {
        float w = sel[e] * inv;
        int slot = atomicAdd(&counts[e], 1);
        lists[e * NT + slot] = n;
        wl[e * NT + slot] = w;
      }
    }
  }
}

// GEMM1 per expert: h[slot, f] = gelu( x[tok(slot), :] @ w1[e] + b1[e] ), bf16 out.
// Tile 128x128, BK=64, 4 waves (2x2), 16x16x32 bf16 MFMA, XOR-swizzled LDS.
__global__ __launch_bounds__(256) void ffn1_kernel(
    const float* __restrict__ x, const float* __restrict__ w1,
    const float* __restrict__ b1, const int* __restrict__ counts,
    const int* __restrict__ lists, unsigned short* __restrict__ h, int e) {
  int count = counts[e];
  int m0 = blockIdx.y * 128;
  if (m0 >= count) return;
  int n0 = blockIdx.x * 128;
  const float* w1e = w1 + (size_t)e * DM * DF;
  const int* lst = lists + e * NT + m0;

  __shared__ unsigned short lA[128 * 64];
  __shared__ unsigned short lB[128 * 64];

  int tid = threadIdx.x;
  int lane = tid & 63, wid = tid >> 6;
  int wm = wid >> 1, wn = wid & 1;
  int lrow = lane & 15, lk = lane >> 4;

  f32x4 acc[4][4];
#pragma unroll
  for (int m = 0; m < 4; ++m)
#pragma unroll
    for (int n = 0; n < 4; ++n) acc[m][n] = (f32x4)0.0f;

  for (int kt = 0; kt < DM / 64; ++kt) {
    int k0 = kt * 64;
    __syncthreads();
    // stage A (gathered x rows), fp32 -> bf16
#pragma unroll
    for (int p = 0; p < 8; ++p) {
      int idx = p * 256 + tid;
      int r = idx >> 4, c4 = idx & 15;
      int tok = (m0 + r < count) ? lst[r] : lst[0];
      float4 v = *(const float4*)(x + (size_t)tok * DM + k0 + c4 * 4);
      ushort4 bv = make_ushort4(f2bf(v.x), f2bf(v.y), f2bf(v.z), f2bf(v.w));
      int off = r * 128 + ((c4 * 8) ^ ((r & 7) << 4));
      *(ushort4*)((char*)lA + off) = bv;
    }
    // stage B (w1 transpose+convert): lB[n][k]
#pragma unroll
    for (int p = 0; p < 16; ++p) {
      int idx = p * 256 + tid;
      int n = idx & 127, k2 = idx >> 7;
      const float* bp = w1e + (size_t)(k0 + 2 * k2) * DF + n0 + n;
      ushort2 bv = make_ushort2(f2bf(bp[0]), f2bf(bp[DF]));
      int off = n * 128 + ((k2 * 4) ^ ((n & 7) << 4));
      *(ushort2*)((char*)lB + off) = bv;
    }
    __syncthreads();
#pragma unroll
    for (int ks = 0; ks < 2; ++ks) {
      bf16x8 af[4], bfr[4];
#pragma unroll
      for (int m = 0; m < 4; ++m) {
        int row = wm * 64 + m * 16 + lrow;
        int off = row * 128 + (((ks * 64) + lk * 16) ^ ((row & 7) << 4));
        af[m] = *(const bf16x8*)((const char*)lA + off);
      }
#pragma unroll
      for (int n = 0; n < 4; ++n) {
        int row = wn * 64 + n * 16 + lrow;
        int off = row * 128 + (((ks * 64) + lk * 16) ^ ((row & 7) << 4));
        bfr[n] = *(const bf16x8*)((const char*)lB + off);
      }
#pragma unroll
      for (int m = 0; m < 4; ++m)
#pragma unroll
        for (int n = 0; n < 4; ++n)
          acc[m][n] = __builtin_amdgcn_mfma_f32_16x16x32_bf16(af[m], bfr[n], acc[m][n], 0, 0, 0);
    }
  }
  // epilogue: bias + exact gelu -> bf16 h
#pragma unroll
  for (int m = 0; m < 4; ++m) {
    int rbase = m0 + wm * 64 + m * 16 + lk * 4;
#pragma unroll
    for (int n = 0; n < 4; ++n) {
      int col = n0 + wn * 64 + n * 16 + lrow;
      float bias = b1[e * DF + col];
#pragma unroll
      for (int j = 0; j < 4; ++j) {
        float v = acc[m][n][j] + bias;
        float g = 0.5f * v * (1.0f + erff(v * 0.70710678f));
        h[(size_t)(rbase + j) * DF + col] = f2bf(g);
      }
    }
  }
}

// GEMM2 per expert: y = h @ w2[e] + b2[e]; out[tok] += w * y (plain RMW, experts serialized)
__global__ __launch_bounds__(256) void ffn2_kernel(
    const unsigned short* __restrict__ h, const float* __restrict__ w2,
    const float* __restrict__ b2, const int* __restrict__ counts,
    const int* __restrict__ lists, const float* __restrict__ wl,
    float* __restrict__ out, int e) {
  int count = counts[e];
  int m0 = blockIdx.y * 128;
  if (m0 >= count) return;
  int n0 = blockIdx.x * 128;
  const float* w2e = w2 + (size_t)e * DF * DM;

  __shared__ unsigned short lA[128 * 64];
  __shared__ unsigned short lB[128 * 64];

  int tid = threadIdx.x;
  int lane = tid & 63, wid = tid >> 6;
  int wm = wid >> 1, wn = wid & 1;
  int lrow = lane & 15, lk = lane >> 4;

  f32x4 acc[4][4];
#pragma unroll
  for (int m = 0; m < 4; ++m)
#pragma unroll
    for (int n = 0; n < 4; ++n) acc[m][n] = (f32x4)0.0f;

  for (int kt = 0; kt < DF / 64; ++kt) {
    int k0 = kt * 64;
    __syncthreads();
    // stage A from h (bf16 already)
#pragma unroll
    for (int p = 0; p < 8; ++p) {
      int idx = p * 256 + tid;
      int r = idx >> 4, c4 = idx & 15;
      ushort4 v = *(const ushort4*)(h + (size_t)(m0 + r) * DF + k0 + c4 * 4);
      int off = r * 128 + ((c4 * 8) ^ ((r & 7) << 4));
      *(ushort4*)((char*)lA + off) = v;
    }
    // stage B (w2 transpose+convert): lB[n][k]
#pragma unroll
    for (int p = 0; p < 16; ++p) {
      int idx = p * 256 + tid;
      int n = idx & 127, k2 = idx >> 7;
      const float* bp = w2e + (size_t)(k0 + 2 * k2) * DM + n0 + n;
      ushort2 bv = make_ushort2(f2bf(bp[0]), f2bf(bp[DM]));
      int off = n * 128 + ((k2 * 4) ^ ((n & 7) << 4));
      *(ushort2*)((char*)lB + off) = bv;
    }
    __syncthreads();
#pragma unroll
    for (int ks = 0; ks < 2; ++ks) {
      bf16x8 af[4], bfr[4];
#pragma unroll
      for (int m = 0; m < 4; ++m) {
        int row = wm * 64 + m * 16 + lrow;
        int off = row * 128 + (((ks * 64) + lk * 16) ^ ((row & 7) << 4));
        af[m] = *(const bf16x8*)((const char*)lA + off);
      }
#pragma unroll
      for (int n = 0; n < 4; ++n) {
        int row = wn * 64 + n * 16 + lrow;
        int off = row * 128 + (((ks * 64) + lk * 16) ^ ((row & 7) << 4));
        bfr[n] = *(const bf16x8*)((const char*)lB + off);
      }
#pragma unroll
      for (int m = 0; m < 4; ++m)
#pragma unroll
        for (int n = 0; n < 4; ++n)
          acc[m][n] = __builtin_amdgcn_mfma_f32_16x16x32_bf16(af[m], bfr[n], acc[m][n], 0, 0, 0);
    }
  }
  // epilogue: weighted scatter-add into out
#pragma unroll
  for (int m = 0; m < 4; ++m) {
    int rbase = m0 + wm * 64 + m * 16 + lk * 4;
#pragma unroll
    for (int n = 0; n < 4; ++n) {
      int col = n0 + wn * 64 + n * 16 + lrow;
      float bias = b2[e * DM + col];
#pragma unroll
      for (int j = 0; j < 4; ++j) {
        int slot = rbase + j;
        if (slot < count) {
          int tok = lists[e * NT + slot];
          float w = wl[e * NT + slot];
          float* op = out + (size_t)tok * DM + col;
          *op += w * (acc[m][n][j] + bias);
        }
      }
    }
  }
}

extern "C" void kernel_launch(void* const* d_in, const int* in_sizes, int n_in,
                              void* d_out, int out_size, void* d_ws, size_t ws_size,
                              hipStream_t stream) {
  const float* x  = (const float*)d_in[0];
  const float* Wg = (const float*)d_in[1];
  const float* We = (const float*)d_in[2];
  const float* w1 = (const float*)d_in[3];
  const float* b1 = (const float*)d_in[4];
  const float* w2 = (const float*)d_in[5];
  const float* b2 = (const float*)d_in[6];
  float* out = (float*)d_out;

  char* ws = (char*)d_ws;
  int* counts = (int*)ws;                                  // 64 B (pad to 256)
  int* lists = (int*)(ws + 256);                           // 16*4096*4 = 256 KB
  float* wl = (float*)(ws + 256 + 262144);                 // 256 KB
  unsigned short* h = (unsigned short*)(ws + 256 + 2 * 262144);  // 4096*2048*2 = 16 MB

  hipMemsetAsync(out, 0, (size_t)NT * DM * sizeof(float), stream);
  hipMemsetAsync(counts, 0, 64, stream);
  router_kernel<<<NT, 64, 0, stream>>>(x, Wg, We, counts, lists, wl);
  for (int e = 0; e < NEXP; ++e) {
    ffn1_kernel<<<dim3(DF / 128, NT / 128), 256, 0, stream>>>(x, w1, b1, counts, lists, h, e);
    ffn2_kernel<<<dim3(DM / 128, NT / 128), 256, 0, stream>>>(h, w2, b2, counts, lists, wl, out, e);
  }
}

// Round 3
// 725.509 us; speedup vs baseline: 3.1388x; 3.1388x over previous
//
#include <hip/hip_runtime.h>
#include <math.h>

#define NT 4096
#define DM 1024
#define DF 2048
#define NEXP 16

typedef __attribute__((ext_vector_type(8))) short bf16x8;
typedef __attribute__((ext_vector_type(4))) float f32x4;

__device__ __forceinline__ unsigned short f2bf(float f) {
  unsigned int u = __builtin_bit_cast(unsigned int, f);
  u += 0x7fffu + ((u >> 16) & 1u);
  return (unsigned short)(u >> 16);
}

__device__ __forceinline__ void softmax4(float* v) {
  float m = fmaxf(fmaxf(v[0], v[1]), fmaxf(v[2], v[3]));
  float s = 0.f;
#pragma unroll
  for (int j = 0; j < 4; ++j) { v[j] = expf(v[j] - m); s += v[j]; }
  float inv = 1.f / s;
#pragma unroll
  for (int j = 0; j < 4; ++j) v[j] *= inv;
}

// One 256-thread block per token; c = 4*tid; fully unrolled independent loads.
__global__ __launch_bounds__(256) void router2_kernel(
    const float* __restrict__ x, const float* __restrict__ Wg,
    const float* __restrict__ We, int* __restrict__ counts,
    int* __restrict__ lists, float* __restrict__ wl) {
  int n = blockIdx.x;
  int tid = threadIdx.x;
  int c0 = tid * 4;
  float4 xv = *(const float4*)(x + (size_t)n * DM + c0);
  float xa[4] = {xv.x, xv.y, xv.z, xv.w};
  float acc[20];
#pragma unroll
  for (int j = 0; j < 20; ++j) acc[j] = 0.f;
#pragma unroll
  for (int j = 0; j < 4; ++j) {
    int c = c0 + j;
    float4 wg = *(const float4*)(Wg + c * 4);
    acc[0] += xa[j] * wg.x; acc[1] += xa[j] * wg.y;
    acc[2] += xa[j] * wg.z; acc[3] += xa[j] * wg.w;
#pragma unroll
    for (int q = 0; q < 4; ++q) {
      float4 we = *(const float4*)(We + c * 16 + q * 4);
      acc[4 + q * 4 + 0] += xa[j] * we.x;
      acc[4 + q * 4 + 1] += xa[j] * we.y;
      acc[4 + q * 4 + 2] += xa[j] * we.z;
      acc[4 + q * 4 + 3] += xa[j] * we.w;
    }
  }
#pragma unroll
  for (int j = 0; j < 20; ++j) {
    float v = acc[j];
#pragma unroll
    for (int s = 32; s; s >>= 1) v += __shfl_xor(v, s, 64);
    acc[j] = v;
  }
  __shared__ float red[4][20];
  int lane = tid & 63, wv = tid >> 6;
  if (lane == 0) {
#pragma unroll
    for (int j = 0; j < 20; ++j) red[wv][j] = acc[j];
  }
  __syncthreads();
  if (tid == 0) {
    float t[20];
#pragma unroll
    for (int j = 0; j < 20; ++j)
      t[j] = red[0][j] + red[1][j] + red[2][j] + red[3][j];
    float gp[4] = {t[0], t[1], t[2], t[3]};
    softmax4(gp);
    float ep[16];
#pragma unroll
    for (int g = 0; g < 4; ++g) {
      float tt[4] = {t[4 + g * 4], t[5 + g * 4], t[6 + g * 4], t[7 + g * 4]};
      softmax4(tt);
#pragma unroll
      for (int i = 0; i < 4; ++i) ep[g * 4 + i] = tt[i];
    }
    float fp[16];
    bool valid[16];
    int nsel = 0;
#pragma unroll
    for (int g = 0; g < 4; ++g) {
      bool gm = gp[g] >= 0.25f;
#pragma unroll
      for (int i = 0; i < 4; ++i) {
        int e = g * 4 + i;
        bool em = ep[e] >= 0.25f;
        valid[e] = gm && em;
        fp[e] = gp[g] * ep[e];
        nsel += valid[e] ? 1 : 0;
      }
    }
    int m1 = 0; float v1 = -1.f;
#pragma unroll
    for (int e = 0; e < 16; ++e) if (fp[e] > v1) { v1 = fp[e]; m1 = e; }
    int m2 = -1; float v2 = -2.f;
#pragma unroll
    for (int e = 0; e < 16; ++e) if (e != m1 && fp[e] > v2) { v2 = fp[e]; m2 = e; }
    bool use_topk = nsel < 2;
    float sel[16]; float s = 0.f;
#pragma unroll
    for (int e = 0; e < 16; ++e) {
      bool msk = use_topk ? (e == m1 || e == m2) : valid[e];
      sel[e] = msk ? fp[e] : 0.f;
      s += sel[e];
      valid[e] = msk;
    }
    float inv = 1.f / fmaxf(s, 1e-9f);
#pragma unroll
    for (int e = 0; e < 16; ++e) {
      if (valid[e]) {
        float w = sel[e] * inv;
        int slot = atomicAdd(&counts[e], 1);
        lists[e * NT + slot] = n;
        wl[e * NT + slot] = w;
      }
    }
  }
}

// 128-padded exclusive prefix sum of counts -> global h row bases.
__global__ void prefix_kernel(const int* __restrict__ counts, int* __restrict__ base) {
  if (threadIdx.x == 0 && blockIdx.x == 0) {
    int acc = 0;
#pragma unroll
    for (int e = 0; e < NEXP; ++e) {
      base[e] = acc;
      acc += (counts[e] + 127) & ~127;
    }
  }
}

// GEMM1: h[hbase+slot, f] = gelu( x[tok(slot), :] @ w1[e] + b1[e] ), bf16 out.
__global__ __launch_bounds__(256) void ffn1_kernel(
    const float* __restrict__ x, const float* __restrict__ w1,
    const float* __restrict__ b1, const int* __restrict__ counts,
    const int* __restrict__ lists, const int* __restrict__ base,
    unsigned short* __restrict__ h, int cap, int e_arg) {
  int e = (e_arg >= 0) ? e_arg : (int)blockIdx.z;
  int count = counts[e];
  int m0 = blockIdx.y * 128;
  if (m0 >= count) return;
  int hbase = base[e];
  if (hbase + m0 + 128 > cap) return;  // overflow guard
  int n0 = blockIdx.x * 128;
  const float* w1e = w1 + (size_t)e * DM * DF;
  const int* lst = lists + e * NT + m0;

  __shared__ unsigned short lA[128 * 64];
  __shared__ unsigned short lB[128 * 64];

  int tid = threadIdx.x;
  int lane = tid & 63, wid = tid >> 6;
  int wm = wid >> 1, wn = wid & 1;
  int lrow = lane & 15, lk = lane >> 4;

  f32x4 acc[4][4];
#pragma unroll
  for (int m = 0; m < 4; ++m)
#pragma unroll
    for (int n = 0; n < 4; ++n) acc[m][n] = (f32x4)0.0f;

  for (int kt = 0; kt < DM / 64; ++kt) {
    int k0 = kt * 64;
    __syncthreads();
#pragma unroll
    for (int p = 0; p < 8; ++p) {
      int idx = p * 256 + tid;
      int r = idx >> 4, c4 = idx & 15;
      int tok = (m0 + r < count) ? lst[r] : lst[0];
      float4 v = *(const float4*)(x + (size_t)tok * DM + k0 + c4 * 4);
      ushort4 bv = make_ushort4(f2bf(v.x), f2bf(v.y), f2bf(v.z), f2bf(v.w));
      int off = r * 128 + ((c4 * 8) ^ ((r & 7) << 4));
      *(ushort4*)((char*)lA + off) = bv;
    }
#pragma unroll
    for (int p = 0; p < 16; ++p) {
      int idx = p * 256 + tid;
      int n = idx & 127, k2 = idx >> 7;
      const float* bp = w1e + (size_t)(k0 + 2 * k2) * DF + n0 + n;
      ushort2 bv = make_ushort2(f2bf(bp[0]), f2bf(bp[DF]));
      int off = n * 128 + ((k2 * 4) ^ ((n & 7) << 4));
      *(ushort2*)((char*)lB + off) = bv;
    }
    __syncthreads();
#pragma unroll
    for (int ks = 0; ks < 2; ++ks) {
      bf16x8 af[4], bfr[4];
#pragma unroll
      for (int m = 0; m < 4; ++m) {
        int row = wm * 64 + m * 16 + lrow;
        int off = row * 128 + (((ks * 64) + lk * 16) ^ ((row & 7) << 4));
        af[m] = *(const bf16x8*)((const char*)lA + off);
      }
#pragma unroll
      for (int n = 0; n < 4; ++n) {
        int row = wn * 64 + n * 16 + lrow;
        int off = row * 128 + (((ks * 64) + lk * 16) ^ ((row & 7) << 4));
        bfr[n] = *(const bf16x8*)((const char*)lB + off);
      }
#pragma unroll
      for (int m = 0; m < 4; ++m)
#pragma unroll
        for (int n = 0; n < 4; ++n)
          acc[m][n] = __builtin_amdgcn_mfma_f32_16x16x32_bf16(af[m], bfr[n], acc[m][n], 0, 0, 0);
    }
  }
#pragma unroll
  for (int m = 0; m < 4; ++m) {
    int rbase = hbase + m0 + wm * 64 + m * 16 + lk * 4;
#pragma unroll
    for (int n = 0; n < 4; ++n) {
      int col = n0 + wn * 64 + n * 16 + lrow;
      float bias = b1[e * DF + col];
#pragma unroll
      for (int j = 0; j < 4; ++j) {
        float v = acc[m][n][j] + bias;
        float g = 0.5f * v * (1.0f + erff(v * 0.70710678f));
        h[(size_t)(rbase + j) * DF + col] = f2bf(g);
      }
    }
  }
}

// GEMM2: y = h @ w2[e] + b2[e]; out[tok] += w * y via atomicAdd (experts concurrent).
__global__ __launch_bounds__(256) void ffn2_kernel(
    const unsigned short* __restrict__ h, const float* __restrict__ w2,
    const float* __restrict__ b2, const int* __restrict__ counts,
    const int* __restrict__ lists, const int* __restrict__ base,
    const float* __restrict__ wl, float* __restrict__ out, int cap, int e_arg) {
  int e = (e_arg >= 0) ? e_arg : (int)blockIdx.z;
  int count = counts[e];
  int m0 = blockIdx.y * 128;
  if (m0 >= count) return;
  int hbase = base[e];
  if (hbase + m0 + 128 > cap) return;
  int n0 = blockIdx.x * 128;
  const float* w2e = w2 + (size_t)e * DF * DM;

  __shared__ unsigned short lA[128 * 64];
  __shared__ unsigned short lB[128 * 64];

  int tid = threadIdx.x;
  int lane = tid & 63, wid = tid >> 6;
  int wm = wid >> 1, wn = wid & 1;
  int lrow = lane & 15, lk = lane >> 4;

  f32x4 acc[4][4];
#pragma unroll
  for (int m = 0; m < 4; ++m)
#pragma unroll
    for (int n = 0; n < 4; ++n) acc[m][n] = (f32x4)0.0f;

  for (int kt = 0; kt < DF / 64; ++kt) {
    int k0 = kt * 64;
    __syncthreads();
#pragma unroll
    for (int p = 0; p < 8; ++p) {
      int idx = p * 256 + tid;
      int r = idx >> 4, c4 = idx & 15;
      ushort4 v = *(const ushort4*)(h + (size_t)(hbase + m0 + r) * DF + k0 + c4 * 4);
      int off = r * 128 + ((c4 * 8) ^ ((r & 7) << 4));
      *(ushort4*)((char*)lA + off) = v;
    }
#pragma unroll
    for (int p = 0; p < 16; ++p) {
      int idx = p * 256 + tid;
      int n = idx & 127, k2 = idx >> 7;
      const float* bp = w2e + (size_t)(k0 + 2 * k2) * DM + n0 + n;
      ushort2 bv = make_ushort2(f2bf(bp[0]), f2bf(bp[DM]));
      int off = n * 128 + ((k2 * 4) ^ ((n & 7) << 4));
      *(ushort2*)((char*)lB + off) = bv;
    }
    __syncthreads();
#pragma unroll
    for (int ks = 0; ks < 2; ++ks) {
      bf16x8 af[4], bfr[4];
#pragma unroll
      for (int m = 0; m < 4; ++m) {
        int row = wm * 64 + m * 16 + lrow;
        int off = row * 128 + (((ks * 64) + lk * 16) ^ ((row & 7) << 4));
        af[m] = *(const bf16x8*)((const char*)lA + off);
      }
#pragma unroll
      for (int n = 0; n < 4; ++n) {
        int row = wn * 64 + n * 16 + lrow;
        int off = row * 128 + (((ks * 64) + lk * 16) ^ ((row & 7) << 4));
        bfr[n] = *(const bf16x8*)((const char*)lB + off);
      }
#pragma unroll
      for (int m = 0; m < 4; ++m)
#pragma unroll
        for (int n = 0; n < 4; ++n)
          acc[m][n] = __builtin_amdgcn_mfma_f32_16x16x32_bf16(af[m], bfr[n], acc[m][n], 0, 0, 0);
    }
  }
#pragma unroll
  for (int m = 0; m < 4; ++m) {
    int rbase = m0 + wm * 64 + m * 16 + lk * 4;
#pragma unroll
    for (int n = 0; n < 4; ++n) {
      int col = n0 + wn * 64 + n * 16 + lrow;
      float bias = b2[e * DM + col];
#pragma unroll
      for (int j = 0; j < 4; ++j) {
        int slot = rbase + j;
        if (slot < count) {
          int tok = lists[e * NT + slot];
          float w = wl[e * NT + slot];
          atomicAdd(out + (size_t)tok * DM + col, w * (acc[m][n][j] + bias));
        }
      }
    }
  }
}

extern "C" void kernel_launch(void* const* d_in, const int* in_sizes, int n_in,
                              void* d_out, int out_size, void* d_ws, size_t ws_size,
                              hipStream_t stream) {
  const float* x  = (const float*)d_in[0];
  const float* Wg = (const float*)d_in[1];
  const float* We = (const float*)d_in[2];
  const float* w1 = (const float*)d_in[3];
  const float* b1 = (const float*)d_in[4];
  const float* w2 = (const float*)d_in[5];
  const float* b2 = (const float*)d_in[6];
  float* out = (float*)d_out;

  char* ws = (char*)d_ws;
  int* counts = (int*)ws;                                   // 64 B
  int* base   = (int*)(ws + 256);                           // 64 B
  int* lists  = (int*)(ws + 1024);                          // 256 KB
  float* wl   = (float*)(ws + 1024 + NEXP * NT * 4);        // 256 KB
  unsigned short* h = (unsigned short*)(ws + (1 << 20));    // cap rows x DF bf16

  hipMemsetAsync(out, 0, (size_t)NT * DM * sizeof(float), stream);
  hipMemsetAsync(counts, 0, 64, stream);
  router2_kernel<<<NT, 256, 0, stream>>>(x, Wg, We, counts, lists, wl);

  long cap_rows = ((long)ws_size - (1 << 20)) / (DF * 2);
  if (cap_rows >= 24576) {
    int cap = (int)(cap_rows > 65536 ? 65536 : cap_rows);
    prefix_kernel<<<1, 64, 0, stream>>>(counts, base);
    ffn1_kernel<<<dim3(DF / 128, NT / 128, NEXP), 256, 0, stream>>>(
        x, w1, b1, counts, lists, base, h, cap, -1);
    ffn2_kernel<<<dim3(DM / 128, NT / 128, NEXP), 256, 0, stream>>>(
        h, w2, b2, counts, lists, base, wl, out, cap, -1);
  } else {
    // scratch too small for global h: serialized per-expert fallback (h reused)
    hipMemsetAsync(base, 0, 64, stream);
    for (int e = 0; e < NEXP; ++e) {
      ffn1_kernel<<<dim3(DF / 128, NT / 128, 1), 256, 0, stream>>>(
          x, w1, b1, counts, lists, base, h, NT, e);
      ffn2_kernel<<<dim3(DM / 128, NT / 128, 1), 256, 0, stream>>>(
          h, w2, b2, counts, lists, base, wl, out, NT, e);
    }
  }
}

// Round 4
// 509.769 us; speedup vs baseline: 4.4672x; 1.4232x over previous
//
#include <hip/hip_runtime.h>
#include <math.h>

#define NT 4096
#define DM 1024
#define DF 2048
#define NEXP 16

typedef __attribute__((ext_vector_type(8))) short bf16x8;
typedef __attribute__((ext_vector_type(4))) float f32x4;

__device__ __forceinline__ unsigned short f2bf(float f) {
  unsigned int u = __builtin_bit_cast(unsigned int, f);
  u += 0x7fffu + ((u >> 16) & 1u);
  return (unsigned short)(u >> 16);
}

__device__ __forceinline__ void gload_lds16(const void* g, void* l) {
  __builtin_amdgcn_global_load_lds(
      (__attribute__((address_space(1))) void*)g,
      (__attribute__((address_space(3))) void*)l, 16, 0, 0);
}

__device__ __forceinline__ void softmax4(float* v) {
  float m = fmaxf(fmaxf(v[0], v[1]), fmaxf(v[2], v[3]));
  float s = 0.f;
#pragma unroll
  for (int j = 0; j < 4; ++j) { v[j] = expf(v[j] - m); s += v[j]; }
  float inv = 1.f / s;
#pragma unroll
  for (int j = 0; j < 4; ++j) v[j] *= inv;
}

// ---------------- router ----------------
__global__ __launch_bounds__(256) void router2_kernel(
    const float* __restrict__ x, const float* __restrict__ Wg,
    const float* __restrict__ We, int* __restrict__ counts,
    int* __restrict__ lists, float* __restrict__ wl) {
  int n = blockIdx.x;
  int tid = threadIdx.x;
  int c0 = tid * 4;
  float4 xv = *(const float4*)(x + (size_t)n * DM + c0);
  float xa[4] = {xv.x, xv.y, xv.z, xv.w};
  float acc[20];
#pragma unroll
  for (int j = 0; j < 20; ++j) acc[j] = 0.f;
#pragma unroll
  for (int j = 0; j < 4; ++j) {
    int c = c0 + j;
    float4 wg = *(const float4*)(Wg + c * 4);
    acc[0] += xa[j] * wg.x; acc[1] += xa[j] * wg.y;
    acc[2] += xa[j] * wg.z; acc[3] += xa[j] * wg.w;
#pragma unroll
    for (int q = 0; q < 4; ++q) {
      float4 we = *(const float4*)(We + c * 16 + q * 4);
      acc[4 + q * 4 + 0] += xa[j] * we.x;
      acc[4 + q * 4 + 1] += xa[j] * we.y;
      acc[4 + q * 4 + 2] += xa[j] * we.z;
      acc[4 + q * 4 + 3] += xa[j] * we.w;
    }
  }
#pragma unroll
  for (int j = 0; j < 20; ++j) {
    float v = acc[j];
#pragma unroll
    for (int s = 32; s; s >>= 1) v += __shfl_xor(v, s, 64);
    acc[j] = v;
  }
  __shared__ float red[4][20];
  int lane = tid & 63, wv = tid >> 6;
  if (lane == 0) {
#pragma unroll
    for (int j = 0; j < 20; ++j) red[wv][j] = acc[j];
  }
  __syncthreads();
  if (tid == 0) {
    float t[20];
#pragma unroll
    for (int j = 0; j < 20; ++j)
      t[j] = red[0][j] + red[1][j] + red[2][j] + red[3][j];
    float gp[4] = {t[0], t[1], t[2], t[3]};
    softmax4(gp);
    float ep[16];
#pragma unroll
    for (int g = 0; g < 4; ++g) {
      float tt[4] = {t[4 + g * 4], t[5 + g * 4], t[6 + g * 4], t[7 + g * 4]};
      softmax4(tt);
#pragma unroll
      for (int i = 0; i < 4; ++i) ep[g * 4 + i] = tt[i];
    }
    float fp[16];
    bool valid[16];
    int nsel = 0;
#pragma unroll
    for (int g = 0; g < 4; ++g) {
      bool gm = gp[g] >= 0.25f;
#pragma unroll
      for (int i = 0; i < 4; ++i) {
        int e = g * 4 + i;
        bool em = ep[e] >= 0.25f;
        valid[e] = gm && em;
        fp[e] = gp[g] * ep[e];
        nsel += valid[e] ? 1 : 0;
      }
    }
    int m1 = 0; float v1 = -1.f;
#pragma unroll
    for (int e = 0; e < 16; ++e) if (fp[e] > v1) { v1 = fp[e]; m1 = e; }
    int m2 = -1; float v2 = -2.f;
#pragma unroll
    for (int e = 0; e < 16; ++e) if (e != m1 && fp[e] > v2) { v2 = fp[e]; m2 = e; }
    bool use_topk = nsel < 2;
    float sel[16]; float s = 0.f;
#pragma unroll
    for (int e = 0; e < 16; ++e) {
      bool msk = use_topk ? (e == m1 || e == m2) : valid[e];
      sel[e] = msk ? fp[e] : 0.f;
      s += sel[e];
      valid[e] = msk;
    }
    float inv = 1.f / fmaxf(s, 1e-9f);
#pragma unroll
    for (int e = 0; e < 16; ++e) {
      if (valid[e]) {
        float w = sel[e] * inv;
        int slot = atomicAdd(&counts[e], 1);
        lists[e * NT + slot] = n;
        wl[e * NT + slot] = w;
      }
    }
  }
}

__global__ void prefix_kernel(const int* __restrict__ counts, int* __restrict__ base) {
  if (threadIdx.x == 0 && blockIdx.x == 0) {
    int acc = 0;
#pragma unroll
    for (int e = 0; e < NEXP; ++e) {
      base[e] = acc;
      acc += (counts[e] + 127) & ~127;
    }
  }
}

// ---------------- prep: convert / transpose ----------------
// x fp32 [NT][DM] -> bf16 same layout
__global__ __launch_bounds__(256) void xconv_kernel(const float* __restrict__ x,
                                                    unsigned short* __restrict__ xb) {
  size_t i = (size_t)blockIdx.x * 256 + threadIdx.x;  // float4 index
  float4 v = *(const float4*)(x + i * 4);
  ushort4 o = make_ushort4(f2bf(v.x), f2bf(v.y), f2bf(v.z), f2bf(v.w));
  *(ushort4*)(xb + i * 4) = o;
}

// in fp32 [E][K][N] -> out bf16 [E][N][K], 64x64 LDS tiles
__global__ __launch_bounds__(256) void wtrans_kernel(
    const float* __restrict__ in, unsigned short* __restrict__ outp, int K, int N) {
  int e = blockIdx.z;
  int n0 = blockIdx.x * 64;
  int k0 = blockIdx.y * 64;
  const float* src = in + (size_t)e * K * N;
  unsigned short* dst = outp + (size_t)e * K * N;
  __shared__ unsigned short t[64][65];
  int tid = threadIdx.x;
#pragma unroll
  for (int it = 0; it < 4; ++it) {
    int idx = it * 256 + tid;
    int r = idx >> 4, c4 = (idx & 15) << 2;
    float4 v = *(const float4*)(src + (size_t)(k0 + r) * N + n0 + c4);
    t[r][c4 + 0] = f2bf(v.x);
    t[r][c4 + 1] = f2bf(v.y);
    t[r][c4 + 2] = f2bf(v.z);
    t[r][c4 + 3] = f2bf(v.w);
  }
  __syncthreads();
#pragma unroll
  for (int it = 0; it < 4; ++it) {
    int idx = it * 256 + tid;
    int r = idx >> 4, c4 = (idx & 15) << 2;  // r = n-local, c4 = k-local
    ushort4 o;
    o.x = t[c4 + 0][r]; o.y = t[c4 + 1][r];
    o.z = t[c4 + 2][r]; o.w = t[c4 + 3][r];
    *(ushort4*)(dst + (size_t)(n0 + r) * K + k0 + c4) = o;
  }
}

// ---------------- new GEMMs: global_load_lds staging, bf16 inputs ----------------
// GEMM1: h[hbase+slot, :] = gelu(xb[tok] @ w1t[e]^T + b1[e]); w1t layout [E][DF][DM]
__global__ __launch_bounds__(256) void ffn1b_kernel(
    const unsigned short* __restrict__ xb, const unsigned short* __restrict__ wt,
    const float* __restrict__ b1, const int* __restrict__ counts,
    const int* __restrict__ lists, const int* __restrict__ base,
    unsigned short* __restrict__ h, int cap) {
  int e = blockIdx.z;
  int count = counts[e];
  int m0 = blockIdx.y * 128;
  if (m0 >= count) return;
  int hbase = base[e];
  if (hbase + m0 + 128 > cap) return;
  int n0 = blockIdx.x * 128;
  const unsigned short* we = wt + (size_t)e * DM * DF;  // [DF][DM]
  const int* lst = lists + e * NT + m0;

  __shared__ unsigned short lA[128 * 64];
  __shared__ unsigned short lB[128 * 64];

  int tid = threadIdx.x, lane = tid & 63, wid = tid >> 6;
  int wm = wid >> 1, wn = wid & 1;
  int lrow = lane & 15, lk = lane >> 4;
  int chunk = lane & 7, row_l = lane >> 3;

  // staging: wave wid, call c stages rows wid*32+c*8+row_l, dest chunk = lane&7,
  // source chunk = chunk ^ (row&7)  (inverse swizzle on global side, LDS linear)
  const char* asrc[4];
  const char* bsrc[4];
#pragma unroll
  for (int c = 0; c < 4; ++c) {
    int r = wid * 32 + c * 8 + row_l;
    int sc = chunk ^ (r & 7);
    int rr = (m0 + r < count) ? r : 0;
    int tok = lst[rr];
    asrc[c] = (const char*)xb + (size_t)tok * DM * 2 + sc * 16;
    bsrc[c] = (const char*)we + (size_t)(n0 + r) * DM * 2 + sc * 16;
  }

  f32x4 acc[4][4];
#pragma unroll
  for (int m = 0; m < 4; ++m)
#pragma unroll
    for (int n = 0; n < 4; ++n) acc[m][n] = (f32x4)0.0f;

  for (int kt = 0; kt < DM / 64; ++kt) {
    __syncthreads();
#pragma unroll
    for (int c = 0; c < 4; ++c) {
      void* la = (void*)(lA + (wid * 32 + c * 8) * 64);
      void* lb = (void*)(lB + (wid * 32 + c * 8) * 64);
      gload_lds16(asrc[c] + kt * 128, la);
      gload_lds16(bsrc[c] + kt * 128, lb);
    }
    __syncthreads();
#pragma unroll
    for (int ks = 0; ks < 2; ++ks) {
      bf16x8 af[4], bfr[4];
#pragma unroll
      for (int m = 0; m < 4; ++m) {
        int row = wm * 64 + m * 16 + lrow;
        int off = row * 128 + (((ks * 64) + lk * 16) ^ ((row & 7) << 4));
        af[m] = *(const bf16x8*)((const char*)lA + off);
      }
#pragma unroll
      for (int n = 0; n < 4; ++n) {
        int row = wn * 64 + n * 16 + lrow;
        int off = row * 128 + (((ks * 64) + lk * 16) ^ ((row & 7) << 4));
        bfr[n] = *(const bf16x8*)((const char*)lB + off);
      }
#pragma unroll
      for (int m = 0; m < 4; ++m)
#pragma unroll
        for (int n = 0; n < 4; ++n)
          acc[m][n] = __builtin_amdgcn_mfma_f32_16x16x32_bf16(af[m], bfr[n], acc[m][n], 0, 0, 0);
    }
  }
#pragma unroll
  for (int m = 0; m < 4; ++m) {
    int rbase = hbase + m0 + wm * 64 + m * 16 + lk * 4;
#pragma unroll
    for (int n = 0; n < 4; ++n) {
      int col = n0 + wn * 64 + n * 16 + lrow;
      float bias = b1[e * DF + col];
#pragma unroll
      for (int j = 0; j < 4; ++j) {
        float v = acc[m][n][j] + bias;
        float g = 0.5f * v * (1.0f + erff(v * 0.70710678f));
        h[(size_t)(rbase + j) * DF + col] = f2bf(g);
      }
    }
  }
}

// GEMM2: out[tok] += w * (h @ w2t[e]^T + b2[e]); w2t layout [E][DM][DF]
__global__ __launch_bounds__(256) void ffn2b_kernel(
    const unsigned short* __restrict__ h, const unsigned short* __restrict__ wt,
    const float* __restrict__ b2, const int* __restrict__ counts,
    const int* __restrict__ lists, const int* __restrict__ base,
    const float* __restrict__ wl, float* __restrict__ out, int cap) {
  int e = blockIdx.z;
  int count = counts[e];
  int m0 = blockIdx.y * 128;
  if (m0 >= count) return;
  int hbase = base[e];
  if (hbase + m0 + 128 > cap) return;
  int n0 = blockIdx.x * 128;
  const unsigned short* we = wt + (size_t)e * DM * DF;  // [DM][DF]

  __shared__ unsigned short lA[128 * 64];
  __shared__ unsigned short lB[128 * 64];

  int tid = threadIdx.x, lane = tid & 63, wid = tid >> 6;
  int wm = wid >> 1, wn = wid & 1;
  int lrow = lane & 15, lk = lane >> 4;
  int chunk = lane & 7, row_l = lane >> 3;

  const char* asrc[4];
  const char* bsrc[4];
#pragma unroll
  for (int c = 0; c < 4; ++c) {
    int r = wid * 32 + c * 8 + row_l;
    int sc = chunk ^ (r & 7);
    asrc[c] = (const char*)h + (size_t)(hbase + m0 + r) * DF * 2 + sc * 16;
    bsrc[c] = (const char*)we + (size_t)(n0 + r) * DF * 2 + sc * 16;
  }

  f32x4 acc[4][4];
#pragma unroll
  for (int m = 0; m < 4; ++m)
#pragma unroll
    for (int n = 0; n < 4; ++n) acc[m][n] = (f32x4)0.0f;

  for (int kt = 0; kt < DF / 64; ++kt) {
    __syncthreads();
#pragma unroll
    for (int c = 0; c < 4; ++c) {
      void* la = (void*)(lA + (wid * 32 + c * 8) * 64);
      void* lb = (void*)(lB + (wid * 32 + c * 8) * 64);
      gload_lds16(asrc[c] + kt * 128, la);
      gload_lds16(bsrc[c] + kt * 128, lb);
    }
    __syncthreads();
#pragma unroll
    for (int ks = 0; ks < 2; ++ks) {
      bf16x8 af[4], bfr[4];
#pragma unroll
      for (int m = 0; m < 4; ++m) {
        int row = wm * 64 + m * 16 + lrow;
        int off = row * 128 + (((ks * 64) + lk * 16) ^ ((row & 7) << 4));
        af[m] = *(const bf16x8*)((const char*)lA + off);
      }
#pragma unroll
      for (int n = 0; n < 4; ++n) {
        int row = wn * 64 + n * 16 + lrow;
        int off = row * 128 + (((ks * 64) + lk * 16) ^ ((row & 7) << 4));
        bfr[n] = *(const bf16x8*)((const char*)lB + off);
      }
#pragma unroll
      for (int m = 0; m < 4; ++m)
#pragma unroll
        for (int n = 0; n < 4; ++n)
          acc[m][n] = __builtin_amdgcn_mfma_f32_16x16x32_bf16(af[m], bfr[n], acc[m][n], 0, 0, 0);
    }
  }
#pragma unroll
  for (int m = 0; m < 4; ++m) {
    int rbase = m0 + wm * 64 + m * 16 + lk * 4;
#pragma unroll
    for (int n = 0; n < 4; ++n) {
      int col = n0 + wn * 64 + n * 16 + lrow;
      float bias = b2[e * DM + col];
#pragma unroll
      for (int j = 0; j < 4; ++j) {
        int slot = rbase + j;
        if (slot < count) {
          int tok = lists[e * NT + slot];
          float w = wl[e * NT + slot];
          atomicAdd(out + (size_t)tok * DM + col, w * (acc[m][n][j] + bias));
        }
      }
    }
  }
}

// ---------------- fallback GEMMs (R3, fp32 reg-staged) ----------------
__global__ __launch_bounds__(256) void ffn1_kernel(
    const float* __restrict__ x, const float* __restrict__ w1,
    const float* __restrict__ b1, const int* __restrict__ counts,
    const int* __restrict__ lists, const int* __restrict__ base,
    unsigned short* __restrict__ h, int cap, int e_arg) {
  int e = (e_arg >= 0) ? e_arg : (int)blockIdx.z;
  int count = counts[e];
  int m0 = blockIdx.y * 128;
  if (m0 >= count) return;
  int hbase = base[e];
  if (hbase + m0 + 128 > cap) return;
  int n0 = blockIdx.x * 128;
  const float* w1e = w1 + (size_t)e * DM * DF;
  const int* lst = lists + e * NT + m0;
  __shared__ unsigned short lA[128 * 64];
  __shared__ unsigned short lB[128 * 64];
  int tid = threadIdx.x;
  int lane = tid & 63, wid = tid >> 6;
  int wm = wid >> 1, wn = wid & 1;
  int lrow = lane & 15, lk = lane >> 4;
  f32x4 acc[4][4];
#pragma unroll
  for (int m = 0; m < 4; ++m)
#pragma unroll
    for (int n = 0; n < 4; ++n) acc[m][n] = (f32x4)0.0f;
  for (int kt = 0; kt < DM / 64; ++kt) {
    int k0 = kt * 64;
    __syncthreads();
#pragma unroll
    for (int p = 0; p < 8; ++p) {
      int idx = p * 256 + tid;
      int r = idx >> 4, c4 = idx & 15;
      int tok = (m0 + r < count) ? lst[r] : lst[0];
      float4 v = *(const float4*)(x + (size_t)tok * DM + k0 + c4 * 4);
      ushort4 bv = make_ushort4(f2bf(v.x), f2bf(v.y), f2bf(v.z), f2bf(v.w));
      int off = r * 128 + ((c4 * 8) ^ ((r & 7) << 4));
      *(ushort4*)((char*)lA + off) = bv;
    }
#pragma unroll
    for (int p = 0; p < 16; ++p) {
      int idx = p * 256 + tid;
      int n = idx & 127, k2 = idx >> 7;
      const float* bp = w1e + (size_t)(k0 + 2 * k2) * DF + n0 + n;
      ushort2 bv = make_ushort2(f2bf(bp[0]), f2bf(bp[DF]));
      int off = n * 128 + ((k2 * 4) ^ ((n & 7) << 4));
      *(ushort2*)((char*)lB + off) = bv;
    }
    __syncthreads();
#pragma unroll
    for (int ks = 0; ks < 2; ++ks) {
      bf16x8 af[4], bfr[4];
#pragma unroll
      for (int m = 0; m < 4; ++m) {
        int row = wm * 64 + m * 16 + lrow;
        int off = row * 128 + (((ks * 64) + lk * 16) ^ ((row & 7) << 4));
        af[m] = *(const bf16x8*)((const char*)lA + off);
      }
#pragma unroll
      for (int n = 0; n < 4; ++n) {
        int row = wn * 64 + n * 16 + lrow;
        int off = row * 128 + (((ks * 64) + lk * 16) ^ ((row & 7) << 4));
        bfr[n] = *(const bf16x8*)((const char*)lB + off);
      }
#pragma unroll
      for (int m = 0; m < 4; ++m)
#pragma unroll
        for (int n = 0; n < 4; ++n)
          acc[m][n] = __builtin_amdgcn_mfma_f32_16x16x32_bf16(af[m], bfr[n], acc[m][n], 0, 0, 0);
    }
  }
#pragma unroll
  for (int m = 0; m < 4; ++m) {
    int rbase = hbase + m0 + wm * 64 + m * 16 + lk * 4;
#pragma unroll
    for (int n = 0; n < 4; ++n) {
      int col = n0 + wn * 64 + n * 16 + lrow;
      float bias = b1[e * DF + col];
#pragma unroll
      for (int j = 0; j < 4; ++j) {
        float v = acc[m][n][j] + bias;
        float g = 0.5f * v * (1.0f + erff(v * 0.70710678f));
        h[(size_t)(rbase + j) * DF + col] = f2bf(g);
      }
    }
  }
}

__global__ __launch_bounds__(256) void ffn2_kernel(
    const unsigned short* __restrict__ h, const float* __restrict__ w2,
    const float* __restrict__ b2, const int* __restrict__ counts,
    const int* __restrict__ lists, const int* __restrict__ base,
    const float* __restrict__ wl, float* __restrict__ out, int cap, int e_arg) {
  int e = (e_arg >= 0) ? e_arg : (int)blockIdx.z;
  int count = counts[e];
  int m0 = blockIdx.y * 128;
  if (m0 >= count) return;
  int hbase = base[e];
  if (hbase + m0 + 128 > cap) return;
  int n0 = blockIdx.x * 128;
  const float* w2e = w2 + (size_t)e * DF * DM;
  __shared__ unsigned short lA[128 * 64];
  __shared__ unsigned short lB[128 * 64];
  int tid = threadIdx.x;
  int lane = tid & 63, wid = tid >> 6;
  int wm = wid >> 1, wn = wid & 1;
  int lrow = lane & 15, lk = lane >> 4;
  f32x4 acc[4][4];
#pragma unroll
  for (int m = 0; m < 4; ++m)
#pragma unroll
    for (int n = 0; n < 4; ++n) acc[m][n] = (f32x4)0.0f;
  for (int kt = 0; kt < DF / 64; ++kt) {
    int k0 = kt * 64;
    __syncthreads();
#pragma unroll
    for (int p = 0; p < 8; ++p) {
      int idx = p * 256 + tid;
      int r = idx >> 4, c4 = idx & 15;
      ushort4 v = *(const ushort4*)(h + (size_t)(hbase + m0 + r) * DF + k0 + c4 * 4);
      int off = r * 128 + ((c4 * 8) ^ ((r & 7) << 4));
      *(ushort4*)((char*)lA + off) = v;
    }
#pragma unroll
    for (int p = 0; p < 16; ++p) {
      int idx = p * 256 + tid;
      int n = idx & 127, k2 = idx >> 7;
      const float* bp = w2e + (size_t)(k0 + 2 * k2) * DM + n0 + n;
      ushort2 bv = make_ushort2(f2bf(bp[0]), f2bf(bp[DM]));
      int off = n * 128 + ((k2 * 4) ^ ((n & 7) << 4));
      *(ushort2*)((char*)lB + off) = bv;
    }
    __syncthreads();
#pragma unroll
    for (int ks = 0; ks < 2; ++ks) {
      bf16x8 af[4], bfr[4];
#pragma unroll
      for (int m = 0; m < 4; ++m) {
        int row = wm * 64 + m * 16 + lrow;
        int off = row * 128 + (((ks * 64) + lk * 16) ^ ((row & 7) << 4));
        af[m] = *(const bf16x8*)((const char*)lA + off);
      }
#pragma unroll
      for (int n = 0; n < 4; ++n) {
        int row = wn * 64 + n * 16 + lrow;
        int off = row * 128 + (((ks * 64) + lk * 16) ^ ((row & 7) << 4));
        bfr[n] = *(const bf16x8*)((const char*)lB + off);
      }
#pragma unroll
      for (int m = 0; m < 4; ++m)
#pragma unroll
        for (int n = 0; n < 4; ++n)
          acc[m][n] = __builtin_amdgcn_mfma_f32_16x16x32_bf16(af[m], bfr[n], acc[m][n], 0, 0, 0);
    }
  }
#pragma unroll
  for (int m = 0; m < 4; ++m) {
    int rbase = m0 + wm * 64 + m * 16 + lk * 4;
#pragma unroll
    for (int n = 0; n < 4; ++n) {
      int col = n0 + wn * 64 + n * 16 + lrow;
      float bias = b2[e * DM + col];
#pragma unroll
      for (int j = 0; j < 4; ++j) {
        int slot = rbase + j;
        if (slot < count) {
          int tok = lists[e * NT + slot];
          float w = wl[e * NT + slot];
          atomicAdd(out + (size_t)tok * DM + col, w * (acc[m][n][j] + bias));
        }
      }
    }
  }
}

extern "C" void kernel_launch(void* const* d_in, const int* in_sizes, int n_in,
                              void* d_out, int out_size, void* d_ws, size_t ws_size,
                              hipStream_t stream) {
  const float* x  = (const float*)d_in[0];
  const float* Wg = (const float*)d_in[1];
  const float* We = (const float*)d_in[2];
  const float* w1 = (const float*)d_in[3];
  const float* b1 = (const float*)d_in[4];
  const float* w2 = (const float*)d_in[5];
  const float* b2 = (const float*)d_in[6];
  float* out = (float*)d_out;

  char* ws = (char*)d_ws;
  int* counts = (int*)ws;                                  // 64 B
  int* base   = (int*)(ws + 256);                          // 64 B
  int* lists  = (int*)(ws + 1024);                         // 256 KB
  float* wl   = (float*)(ws + 1024 + NEXP * NT * 4);       // 256 KB

  hipMemsetAsync(out, 0, (size_t)NT * DM * sizeof(float), stream);
  hipMemsetAsync(counts, 0, 64, stream);
  router2_kernel<<<NT, 256, 0, stream>>>(x, Wg, We, counts, lists, wl);

  const size_t OFF_XB = 1u << 20;           // 8 MB
  const size_t OFF_WT = OFF_XB + ((size_t)NT * DM * 2);     // 9 MB
  const size_t OFF_H  = OFF_WT + ((size_t)NEXP * DM * DF * 2);  // 73 MB
  long cap_new = ((long)ws_size - (long)OFF_H) / (DF * 2);

  if (cap_new >= 20000) {
    // fast path: bf16 pre-converted/transposed weights + global_load_lds GEMMs
    unsigned short* xb = (unsigned short*)(ws + OFF_XB);
    unsigned short* wt = (unsigned short*)(ws + OFF_WT);
    unsigned short* h  = (unsigned short*)(ws + OFF_H);
    int cap = (int)(cap_new > 65536 ? 65536 : cap_new);
    prefix_kernel<<<1, 64, 0, stream>>>(counts, base);
    xconv_kernel<<<(NT * DM / 4) / 256, 256, 0, stream>>>(x, xb);
    wtrans_kernel<<<dim3(DF / 64, DM / 64, NEXP), 256, 0, stream>>>(w1, wt, DM, DF);
    ffn1b_kernel<<<dim3(DF / 128, NT / 128, NEXP), 256, 0, stream>>>(
        xb, wt, b1, counts, lists, base, h, cap);
    wtrans_kernel<<<dim3(DM / 64, DF / 64, NEXP), 256, 0, stream>>>(w2, wt, DF, DM);
    ffn2b_kernel<<<dim3(DM / 128, NT / 128, NEXP), 256, 0, stream>>>(
        h, wt, b2, counts, lists, base, wl, out, cap);
  } else {
    unsigned short* h = (unsigned short*)(ws + OFF_XB);
    long cap_rows = ((long)ws_size - (long)OFF_XB) / (DF * 2);
    if (cap_rows >= 24576) {
      int cap = (int)(cap_rows > 65536 ? 65536 : cap_rows);
      prefix_kernel<<<1, 64, 0, stream>>>(counts, base);
      ffn1_kernel<<<dim3(DF / 128, NT / 128, NEXP), 256, 0, stream>>>(
          x, w1, b1, counts, lists, base, h, cap, -1);
      ffn2_kernel<<<dim3(DM / 128, NT / 128, NEXP), 256, 0, stream>>>(
          h, w2, b2, counts, lists, base, wl, out, cap, -1);
    } else {
      hipMemsetAsync(base, 0, 64, stream);
      for (int e = 0; e < NEXP; ++e) {
        ffn1_kernel<<<dim3(DF / 128, NT / 128, 1), 256, 0, stream>>>(
            x, w1, b1, counts, lists, base, h, NT, e);
        ffn2_kernel<<<dim3(DM / 128, NT / 128, 1), 256, 0, stream>>>(
            h, w2, b2, counts, lists, base, wl, out, NT, e);
      }
    }
  }
}

// Round 5
// 502.055 us; speedup vs baseline: 4.5359x; 1.0154x over previous
//
#include <hip/hip_runtime.h>
#include <math.h>

#define NT 4096
#define DM 1024
#define DF 2048
#define NEXP 16

typedef __attribute__((ext_vector_type(8))) short bf16x8;
typedef __attribute__((ext_vector_type(4))) float f32x4;

__device__ __forceinline__ unsigned short f2bf(float f) {
  unsigned int u = __builtin_bit_cast(unsigned int, f);
  u += 0x7fffu + ((u >> 16) & 1u);
  return (unsigned short)(u >> 16);
}

__device__ __forceinline__ void gload_lds16(const void* g, void* l) {
  __builtin_amdgcn_global_load_lds(
      (__attribute__((address_space(1))) void*)g,
      (__attribute__((address_space(3))) void*)l, 16, 0, 0);
}

__device__ __forceinline__ void softmax4(float* v) {
  float m = fmaxf(fmaxf(v[0], v[1]), fmaxf(v[2], v[3]));
  float s = 0.f;
#pragma unroll
  for (int j = 0; j < 4; ++j) { v[j] = expf(v[j] - m); s += v[j]; }
  float inv = 1.f / s;
#pragma unroll
  for (int j = 0; j < 4; ++j) v[j] *= inv;
}

// ---------------- router ----------------
__global__ __launch_bounds__(256) void router2_kernel(
    const float* __restrict__ x, const float* __restrict__ Wg,
    const float* __restrict__ We, int* __restrict__ counts,
    int* __restrict__ lists, float* __restrict__ wl) {
  int n = blockIdx.x;
  int tid = threadIdx.x;
  int c0 = tid * 4;
  float4 xv = *(const float4*)(x + (size_t)n * DM + c0);
  float xa[4] = {xv.x, xv.y, xv.z, xv.w};
  float acc[20];
#pragma unroll
  for (int j = 0; j < 20; ++j) acc[j] = 0.f;
#pragma unroll
  for (int j = 0; j < 4; ++j) {
    int c = c0 + j;
    float4 wg = *(const float4*)(Wg + c * 4);
    acc[0] += xa[j] * wg.x; acc[1] += xa[j] * wg.y;
    acc[2] += xa[j] * wg.z; acc[3] += xa[j] * wg.w;
#pragma unroll
    for (int q = 0; q < 4; ++q) {
      float4 we = *(const float4*)(We + c * 16 + q * 4);
      acc[4 + q * 4 + 0] += xa[j] * we.x;
      acc[4 + q * 4 + 1] += xa[j] * we.y;
      acc[4 + q * 4 + 2] += xa[j] * we.z;
      acc[4 + q * 4 + 3] += xa[j] * we.w;
    }
  }
#pragma unroll
  for (int j = 0; j < 20; ++j) {
    float v = acc[j];
#pragma unroll
    for (int s = 32; s; s >>= 1) v += __shfl_xor(v, s, 64);
    acc[j] = v;
  }
  __shared__ float red[4][20];
  int lane = tid & 63, wv = tid >> 6;
  if (lane == 0) {
#pragma unroll
    for (int j = 0; j < 20; ++j) red[wv][j] = acc[j];
  }
  __syncthreads();
  if (tid == 0) {
    float t[20];
#pragma unroll
    for (int j = 0; j < 20; ++j)
      t[j] = red[0][j] + red[1][j] + red[2][j] + red[3][j];
    float gp[4] = {t[0], t[1], t[2], t[3]};
    softmax4(gp);
    float ep[16];
#pragma unroll
    for (int g = 0; g < 4; ++g) {
      float tt[4] = {t[4 + g * 4], t[5 + g * 4], t[6 + g * 4], t[7 + g * 4]};
      softmax4(tt);
#pragma unroll
      for (int i = 0; i < 4; ++i) ep[g * 4 + i] = tt[i];
    }
    float fp[16];
    bool valid[16];
    int nsel = 0;
#pragma unroll
    for (int g = 0; g < 4; ++g) {
      bool gm = gp[g] >= 0.25f;
#pragma unroll
      for (int i = 0; i < 4; ++i) {
        int e = g * 4 + i;
        bool em = ep[e] >= 0.25f;
        valid[e] = gm && em;
        fp[e] = gp[g] * ep[e];
        nsel += valid[e] ? 1 : 0;
      }
    }
    int m1 = 0; float v1 = -1.f;
#pragma unroll
    for (int e = 0; e < 16; ++e) if (fp[e] > v1) { v1 = fp[e]; m1 = e; }
    int m2 = -1; float v2 = -2.f;
#pragma unroll
    for (int e = 0; e < 16; ++e) if (e != m1 && fp[e] > v2) { v2 = fp[e]; m2 = e; }
    bool use_topk = nsel < 2;
    float sel[16]; float s = 0.f;
#pragma unroll
    for (int e = 0; e < 16; ++e) {
      bool msk = use_topk ? (e == m1 || e == m2) : valid[e];
      sel[e] = msk ? fp[e] : 0.f;
      s += sel[e];
      valid[e] = msk;
    }
    float inv = 1.f / fmaxf(s, 1e-9f);
#pragma unroll
    for (int e = 0; e < 16; ++e) {
      if (valid[e]) {
        float w = sel[e] * inv;
        int slot = atomicAdd(&counts[e], 1);
        lists[e * NT + slot] = n;
        wl[e * NT + slot] = w;
      }
    }
  }
}

__global__ void prefix_kernel(const int* __restrict__ counts, int* __restrict__ base) {
  if (threadIdx.x == 0 && blockIdx.x == 0) {
    int acc = 0;
#pragma unroll
    for (int e = 0; e < NEXP; ++e) {
      base[e] = acc;
      acc += (counts[e] + 127) & ~127;
    }
  }
}

// ---------------- prep: convert / transpose ----------------
__global__ __launch_bounds__(256) void xconv_kernel(const float* __restrict__ x,
                                                    unsigned short* __restrict__ xb) {
  size_t i = (size_t)blockIdx.x * 256 + threadIdx.x;
  float4 v = *(const float4*)(x + i * 4);
  ushort4 o = make_ushort4(f2bf(v.x), f2bf(v.y), f2bf(v.z), f2bf(v.w));
  *(ushort4*)(xb + i * 4) = o;
}

// in fp32 [E][K][N] -> out bf16 [E][N][K], 64x64 LDS tiles
__global__ __launch_bounds__(256) void wtrans_kernel(
    const float* __restrict__ in, unsigned short* __restrict__ outp, int K, int N) {
  int e = blockIdx.z;
  int n0 = blockIdx.x * 64;
  int k0 = blockIdx.y * 64;
  const float* src = in + (size_t)e * K * N;
  unsigned short* dst = outp + (size_t)e * K * N;
  __shared__ unsigned short t[64][65];
  int tid = threadIdx.x;
#pragma unroll
  for (int it = 0; it < 4; ++it) {
    int idx = it * 256 + tid;
    int r = idx >> 4, c4 = (idx & 15) << 2;
    float4 v = *(const float4*)(src + (size_t)(k0 + r) * N + n0 + c4);
    t[r][c4 + 0] = f2bf(v.x);
    t[r][c4 + 1] = f2bf(v.y);
    t[r][c4 + 2] = f2bf(v.z);
    t[r][c4 + 3] = f2bf(v.w);
  }
  __syncthreads();
#pragma unroll
  for (int it = 0; it < 4; ++it) {
    int idx = it * 256 + tid;
    int r = idx >> 4, c4 = (idx & 15) << 2;
    ushort4 o;
    o.x = t[c4 + 0][r]; o.y = t[c4 + 1][r];
    o.z = t[c4 + 2][r]; o.w = t[c4 + 3][r];
    *(ushort4*)(dst + (size_t)(n0 + r) * K + k0 + c4) = o;
  }
}

// ---------------- GEMMs: dbuf LDS + counted vmcnt prefetch ----------------
// GEMM1: h[hbase+slot, :] = gelu(xb[tok] @ w1t[e]^T + b1[e]); w1t layout [E][DF][DM]
__global__ __launch_bounds__(256) void ffn1b_kernel(
    const unsigned short* __restrict__ xb, const unsigned short* __restrict__ wt,
    const float* __restrict__ b1, const int* __restrict__ counts,
    const int* __restrict__ lists, const int* __restrict__ base,
    unsigned short* __restrict__ h, int cap) {
  int e = blockIdx.z;
  int count = counts[e];
  int m0 = blockIdx.y * 128;
  if (m0 >= count) return;
  int hbase = base[e];
  if (hbase + m0 + 128 > cap) return;
  int n0 = blockIdx.x * 128;
  const unsigned short* we = wt + (size_t)e * DM * DF;
  const int* lst = lists + e * NT + m0;

  __shared__ unsigned short lA[2][128 * 64];
  __shared__ unsigned short lB[2][128 * 64];

  int tid = threadIdx.x, lane = tid & 63, wid = tid >> 6;
  int wm = wid >> 1, wn = wid & 1;
  int lrow = lane & 15, lk = lane >> 4;
  int chunk = lane & 7, row_l = lane >> 3;

  const char* asrc[4];
  const char* bsrc[4];
#pragma unroll
  for (int c = 0; c < 4; ++c) {
    int r = wid * 32 + c * 8 + row_l;
    int sc = chunk ^ (r & 7);
    int rr = (m0 + r < count) ? r : 0;
    int tok = lst[rr];
    asrc[c] = (const char*)xb + (size_t)tok * DM * 2 + sc * 16;
    bsrc[c] = (const char*)we + (size_t)(n0 + r) * DM * 2 + sc * 16;
  }

  f32x4 acc[4][4];
#pragma unroll
  for (int m = 0; m < 4; ++m)
#pragma unroll
    for (int n = 0; n < 4; ++n) acc[m][n] = (f32x4)0.0f;

  auto STAGE = [&](int kt, unsigned short* la, unsigned short* lb) {
#pragma unroll
    for (int c = 0; c < 4; ++c) {
      gload_lds16(asrc[c] + kt * 128, (void*)(la + (wid * 32 + c * 8) * 64));
      gload_lds16(bsrc[c] + kt * 128, (void*)(lb + (wid * 32 + c * 8) * 64));
    }
  };
  auto COMPUTE = [&](const unsigned short* la, const unsigned short* lb) {
#pragma unroll
    for (int ks = 0; ks < 2; ++ks) {
      bf16x8 af[4], bfr[4];
#pragma unroll
      for (int m = 0; m < 4; ++m) {
        int row = wm * 64 + m * 16 + lrow;
        int off = row * 128 + (((ks * 64) + lk * 16) ^ ((row & 7) << 4));
        af[m] = *(const bf16x8*)((const char*)la + off);
      }
#pragma unroll
      for (int n = 0; n < 4; ++n) {
        int row = wn * 64 + n * 16 + lrow;
        int off = row * 128 + (((ks * 64) + lk * 16) ^ ((row & 7) << 4));
        bfr[n] = *(const bf16x8*)((const char*)lb + off);
      }
#pragma unroll
      for (int m = 0; m < 4; ++m)
#pragma unroll
        for (int n = 0; n < 4; ++n)
          acc[m][n] = __builtin_amdgcn_mfma_f32_16x16x32_bf16(af[m], bfr[n], acc[m][n], 0, 0, 0);
    }
  };

  const int KT = DM / 64;  // 16 (even)
  STAGE(0, lA[0], lB[0]);
  for (int kt = 0; kt < KT; kt += 2) {
    // step A: stage kt+1 -> buf1, compute buf0
    STAGE(kt + 1, lA[1], lB[1]);
    asm volatile("s_waitcnt vmcnt(8)" ::: "memory");
    __builtin_amdgcn_s_barrier();
    COMPUTE(lA[0], lB[0]);
    __builtin_amdgcn_s_barrier();
    // step B: stage kt+2 -> buf0 (if any), compute buf1
    if (kt + 2 < KT) {
      STAGE(kt + 2, lA[0], lB[0]);
      asm volatile("s_waitcnt vmcnt(8)" ::: "memory");
    } else {
      asm volatile("s_waitcnt vmcnt(0)" ::: "memory");
    }
    __builtin_amdgcn_s_barrier();
    COMPUTE(lA[1], lB[1]);
    __builtin_amdgcn_s_barrier();
  }

#pragma unroll
  for (int m = 0; m < 4; ++m) {
    int rbase = hbase + m0 + wm * 64 + m * 16 + lk * 4;
#pragma unroll
    for (int n = 0; n < 4; ++n) {
      int col = n0 + wn * 64 + n * 16 + lrow;
      float bias = b1[e * DF + col];
#pragma unroll
      for (int j = 0; j < 4; ++j) {
        float v = acc[m][n][j] + bias;
        float g = 0.5f * v * (1.0f + erff(v * 0.70710678f));
        h[(size_t)(rbase + j) * DF + col] = f2bf(g);
      }
    }
  }
}

// GEMM2: out[tok] += w * (h @ w2t[e]^T + b2[e]); w2t layout [E][DM][DF]
__global__ __launch_bounds__(256) void ffn2b_kernel(
    const unsigned short* __restrict__ h, const unsigned short* __restrict__ wt,
    const float* __restrict__ b2, const int* __restrict__ counts,
    const int* __restrict__ lists, const int* __restrict__ base,
    const float* __restrict__ wl, float* __restrict__ out, int cap) {
  int e = blockIdx.z;
  int count = counts[e];
  int m0 = blockIdx.y * 128;
  if (m0 >= count) return;
  int hbase = base[e];
  if (hbase + m0 + 128 > cap) return;
  int n0 = blockIdx.x * 128;
  const unsigned short* we = wt + (size_t)e * DM * DF;

  __shared__ unsigned short lA[2][128 * 64];
  __shared__ unsigned short lB[2][128 * 64];

  int tid = threadIdx.x, lane = tid & 63, wid = tid >> 6;
  int wm = wid >> 1, wn = wid & 1;
  int lrow = lane & 15, lk = lane >> 4;
  int chunk = lane & 7, row_l = lane >> 3;

  const char* asrc[4];
  const char* bsrc[4];
#pragma unroll
  for (int c = 0; c < 4; ++c) {
    int r = wid * 32 + c * 8 + row_l;
    int sc = chunk ^ (r & 7);
    asrc[c] = (const char*)h + (size_t)(hbase + m0 + r) * DF * 2 + sc * 16;
    bsrc[c] = (const char*)we + (size_t)(n0 + r) * DF * 2 + sc * 16;
  }

  f32x4 acc[4][4];
#pragma unroll
  for (int m = 0; m < 4; ++m)
#pragma unroll
    for (int n = 0; n < 4; ++n) acc[m][n] = (f32x4)0.0f;

  auto STAGE = [&](int kt, unsigned short* la, unsigned short* lb) {
#pragma unroll
    for (int c = 0; c < 4; ++c) {
      gload_lds16(asrc[c] + kt * 128, (void*)(la + (wid * 32 + c * 8) * 64));
      gload_lds16(bsrc[c] + kt * 128, (void*)(lb + (wid * 32 + c * 8) * 64));
    }
  };
  auto COMPUTE = [&](const unsigned short* la, const unsigned short* lb) {
#pragma unroll
    for (int ks = 0; ks < 2; ++ks) {
      bf16x8 af[4], bfr[4];
#pragma unroll
      for (int m = 0; m < 4; ++m) {
        int row = wm * 64 + m * 16 + lrow;
        int off = row * 128 + (((ks * 64) + lk * 16) ^ ((row & 7) << 4));
        af[m] = *(const bf16x8*)((const char*)la + off);
      }
#pragma unroll
      for (int n = 0; n < 4; ++n) {
        int row = wn * 64 + n * 16 + lrow;
        int off = row * 128 + (((ks * 64) + lk * 16) ^ ((row & 7) << 4));
        bfr[n] = *(const bf16x8*)((const char*)lb + off);
      }
#pragma unroll
      for (int m = 0; m < 4; ++m)
#pragma unroll
        for (int n = 0; n < 4; ++n)
          acc[m][n] = __builtin_amdgcn_mfma_f32_16x16x32_bf16(af[m], bfr[n], acc[m][n], 0, 0, 0);
    }
  };

  const int KT = DF / 64;  // 32 (even)
  STAGE(0, lA[0], lB[0]);
  for (int kt = 0; kt < KT; kt += 2) {
    STAGE(kt + 1, lA[1], lB[1]);
    asm volatile("s_waitcnt vmcnt(8)" ::: "memory");
    __builtin_amdgcn_s_barrier();
    COMPUTE(lA[0], lB[0]);
    __builtin_amdgcn_s_barrier();
    if (kt + 2 < KT) {
      STAGE(kt + 2, lA[0], lB[0]);
      asm volatile("s_waitcnt vmcnt(8)" ::: "memory");
    } else {
      asm volatile("s_waitcnt vmcnt(0)" ::: "memory");
    }
    __builtin_amdgcn_s_barrier();
    COMPUTE(lA[1], lB[1]);
    __builtin_amdgcn_s_barrier();
  }

#pragma unroll
  for (int m = 0; m < 4; ++m) {
    int rbase = m0 + wm * 64 + m * 16 + lk * 4;
#pragma unroll
    for (int n = 0; n < 4; ++n) {
      int col = n0 + wn * 64 + n * 16 + lrow;
      float bias = b2[e * DM + col];
#pragma unroll
      for (int j = 0; j < 4; ++j) {
        int slot = rbase + j;
        if (slot < count) {
          int tok = lists[e * NT + slot];
          float w = wl[e * NT + slot];
          atomicAdd(out + (size_t)tok * DM + col, w * (acc[m][n][j] + bias));
        }
      }
    }
  }
}

// ---------------- fallback GEMMs (fp32 reg-staged) ----------------
__global__ __launch_bounds__(256) void ffn1_kernel(
    const float* __restrict__ x, const float* __restrict__ w1,
    const float* __restrict__ b1, const int* __restrict__ counts,
    const int* __restrict__ lists, const int* __restrict__ base,
    unsigned short* __restrict__ h, int cap, int e_arg) {
  int e = (e_arg >= 0) ? e_arg : (int)blockIdx.z;
  int count = counts[e];
  int m0 = blockIdx.y * 128;
  if (m0 >= count) return;
  int hbase = base[e];
  if (hbase + m0 + 128 > cap) return;
  int n0 = blockIdx.x * 128;
  const float* w1e = w1 + (size_t)e * DM * DF;
  const int* lst = lists + e * NT + m0;
  __shared__ unsigned short lA[128 * 64];
  __shared__ unsigned short lB[128 * 64];
  int tid = threadIdx.x;
  int lane = tid & 63, wid = tid >> 6;
  int wm = wid >> 1, wn = wid & 1;
  int lrow = lane & 15, lk = lane >> 4;
  f32x4 acc[4][4];
#pragma unroll
  for (int m = 0; m < 4; ++m)
#pragma unroll
    for (int n = 0; n < 4; ++n) acc[m][n] = (f32x4)0.0f;
  for (int kt = 0; kt < DM / 64; ++kt) {
    int k0 = kt * 64;
    __syncthreads();
#pragma unroll
    for (int p = 0; p < 8; ++p) {
      int idx = p * 256 + tid;
      int r = idx >> 4, c4 = idx & 15;
      int tok = (m0 + r < count) ? lst[r] : lst[0];
      float4 v = *(const float4*)(x + (size_t)tok * DM + k0 + c4 * 4);
      ushort4 bv = make_ushort4(f2bf(v.x), f2bf(v.y), f2bf(v.z), f2bf(v.w));
      int off = r * 128 + ((c4 * 8) ^ ((r & 7) << 4));
      *(ushort4*)((char*)lA + off) = bv;
    }
#pragma unroll
    for (int p = 0; p < 16; ++p) {
      int idx = p * 256 + tid;
      int n = idx & 127, k2 = idx >> 7;
      const float* bp = w1e + (size_t)(k0 + 2 * k2) * DF + n0 + n;
      ushort2 bv = make_ushort2(f2bf(bp[0]), f2bf(bp[DF]));
      int off = n * 128 + ((k2 * 4) ^ ((n & 7) << 4));
      *(ushort2*)((char*)lB + off) = bv;
    }
    __syncthreads();
#pragma unroll
    for (int ks = 0; ks < 2; ++ks) {
      bf16x8 af[4], bfr[4];
#pragma unroll
      for (int m = 0; m < 4; ++m) {
        int row = wm * 64 + m * 16 + lrow;
        int off = row * 128 + (((ks * 64) + lk * 16) ^ ((row & 7) << 4));
        af[m] = *(const bf16x8*)((const char*)lA + off);
      }
#pragma unroll
      for (int n = 0; n < 4; ++n) {
        int row = wn * 64 + n * 16 + lrow;
        int off = row * 128 + (((ks * 64) + lk * 16) ^ ((row & 7) << 4));
        bfr[n] = *(const bf16x8*)((const char*)lB + off);
      }
#pragma unroll
      for (int m = 0; m < 4; ++m)
#pragma unroll
        for (int n = 0; n < 4; ++n)
          acc[m][n] = __builtin_amdgcn_mfma_f32_16x16x32_bf16(af[m], bfr[n], acc[m][n], 0, 0, 0);
    }
  }
#pragma unroll
  for (int m = 0; m < 4; ++m) {
    int rbase = hbase + m0 + wm * 64 + m * 16 + lk * 4;
#pragma unroll
    for (int n = 0; n < 4; ++n) {
      int col = n0 + wn * 64 + n * 16 + lrow;
      float bias = b1[e * DF + col];
#pragma unroll
      for (int j = 0; j < 4; ++j) {
        float v = acc[m][n][j] + bias;
        float g = 0.5f * v * (1.0f + erff(v * 0.70710678f));
        h[(size_t)(rbase + j) * DF + col] = f2bf(g);
      }
    }
  }
}

__global__ __launch_bounds__(256) void ffn2_kernel(
    const unsigned short* __restrict__ h, const float* __restrict__ w2,
    const float* __restrict__ b2, const int* __restrict__ counts,
    const int* __restrict__ lists, const int* __restrict__ base,
    const float* __restrict__ wl, float* __restrict__ out, int cap, int e_arg) {
  int e = (e_arg >= 0) ? e_arg : (int)blockIdx.z;
  int count = counts[e];
  int m0 = blockIdx.y * 128;
  if (m0 >= count) return;
  int hbase = base[e];
  if (hbase + m0 + 128 > cap) return;
  int n0 = blockIdx.x * 128;
  const float* w2e = w2 + (size_t)e * DF * DM;
  __shared__ unsigned short lA[128 * 64];
  __shared__ unsigned short lB[128 * 64];
  int tid = threadIdx.x;
  int lane = tid & 63, wid = tid >> 6;
  int wm = wid >> 1, wn = wid & 1;
  int lrow = lane & 15, lk = lane >> 4;
  f32x4 acc[4][4];
#pragma unroll
  for (int m = 0; m < 4; ++m)
#pragma unroll
    for (int n = 0; n < 4; ++n) acc[m][n] = (f32x4)0.0f;
  for (int kt = 0; kt < DF / 64; ++kt) {
    int k0 = kt * 64;
    __syncthreads();
#pragma unroll
    for (int p = 0; p < 8; ++p) {
      int idx = p * 256 + tid;
      int r = idx >> 4, c4 = idx & 15;
      ushort4 v = *(const ushort4*)(h + (size_t)(hbase + m0 + r) * DF + k0 + c4 * 4);
      int off = r * 128 + ((c4 * 8) ^ ((r & 7) << 4));
      *(ushort4*)((char*)lA + off) = v;
    }
#pragma unroll
    for (int p = 0; p < 16; ++p) {
      int idx = p * 256 + tid;
      int n = idx & 127, k2 = idx >> 7;
      const float* bp = w2e + (size_t)(k0 + 2 * k2) * DM + n0 + n;
      ushort2 bv = make_ushort2(f2bf(bp[0]), f2bf(bp[DM]));
      int off = n * 128 + ((k2 * 4) ^ ((n & 7) << 4));
      *(ushort2*)((char*)lB + off) = bv;
    }
    __syncthreads();
#pragma unroll
    for (int ks = 0; ks < 2; ++ks) {
      bf16x8 af[4], bfr[4];
#pragma unroll
      for (int m = 0; m < 4; ++m) {
        int row = wm * 64 + m * 16 + lrow;
        int off = row * 128 + (((ks * 64) + lk * 16) ^ ((row & 7) << 4));
        af[m] = *(const bf16x8*)((const char*)lA + off);
      }
#pragma unroll
      for (int n = 0; n < 4; ++n) {
        int row = wn * 64 + n * 16 + lrow;
        int off = row * 128 + (((ks * 64) + lk * 16) ^ ((row & 7) << 4));
        bfr[n] = *(const bf16x8*)((const char*)lB + off);
      }
#pragma unroll
      for (int m = 0; m < 4; ++m)
#pragma unroll
        for (int n = 0; n < 4; ++n)
          acc[m][n] = __builtin_amdgcn_mfma_f32_16x16x32_bf16(af[m], bfr[n], acc[m][n], 0, 0, 0);
    }
  }
#pragma unroll
  for (int m = 0; m < 4; ++m) {
    int rbase = m0 + wm * 64 + m * 16 + lk * 4;
#pragma unroll
    for (int n = 0; n < 4; ++n) {
      int col = n0 + wn * 64 + n * 16 + lrow;
      float bias = b2[e * DM + col];
#pragma unroll
      for (int j = 0; j < 4; ++j) {
        int slot = rbase + j;
        if (slot < count) {
          int tok = lists[e * NT + slot];
          float w = wl[e * NT + slot];
          atomicAdd(out + (size_t)tok * DM + col, w * (acc[m][n][j] + bias));
        }
      }
    }
  }
}

extern "C" void kernel_launch(void* const* d_in, const int* in_sizes, int n_in,
                              void* d_out, int out_size, void* d_ws, size_t ws_size,
                              hipStream_t stream) {
  const float* x  = (const float*)d_in[0];
  const float* Wg = (const float*)d_in[1];
  const float* We = (const float*)d_in[2];
  const float* w1 = (const float*)d_in[3];
  const float* b1 = (const float*)d_in[4];
  const float* w2 = (const float*)d_in[5];
  const float* b2 = (const float*)d_in[6];
  float* out = (float*)d_out;

  char* ws = (char*)d_ws;
  int* counts = (int*)ws;                                  // 64 B
  int* base   = (int*)(ws + 256);                          // 64 B
  int* lists  = (int*)(ws + 1024);                         // 256 KB
  float* wl   = (float*)(ws + 1024 + NEXP * NT * 4);       // 256 KB

  hipMemsetAsync(out, 0, (size_t)NT * DM * sizeof(float), stream);
  hipMemsetAsync(counts, 0, 64, stream);
  router2_kernel<<<NT, 256, 0, stream>>>(x, Wg, We, counts, lists, wl);

  const size_t OFF_XB = 1u << 20;                               // 1 MB
  const size_t OFF_WT = OFF_XB + ((size_t)NT * DM * 2);         // +8 MB
  const size_t OFF_H  = OFF_WT + ((size_t)NEXP * DM * DF * 2);  // +64 MB
  long cap_new = ((long)ws_size - (long)OFF_H) / (DF * 2);

  if (cap_new >= 20000) {
    unsigned short* xb = (unsigned short*)(ws + OFF_XB);
    unsigned short* wt = (unsigned short*)(ws + OFF_WT);
    unsigned short* h  = (unsigned short*)(ws + OFF_H);
    int cap = (int)(cap_new > 65536 ? 65536 : cap_new);
    prefix_kernel<<<1, 64, 0, stream>>>(counts, base);
    xconv_kernel<<<(NT * DM / 4) / 256, 256, 0, stream>>>(x, xb);
    wtrans_kernel<<<dim3(DF / 64, DM / 64, NEXP), 256, 0, stream>>>(w1, wt, DM, DF);
    ffn1b_kernel<<<dim3(DF / 128, NT / 128, NEXP), 256, 0, stream>>>(
        xb, wt, b1, counts, lists, base, h, cap);
    wtrans_kernel<<<dim3(DM / 64, DF / 64, NEXP), 256, 0, stream>>>(w2, wt, DF, DM);
    ffn2b_kernel<<<dim3(DM / 128, NT / 128, NEXP), 256, 0, stream>>>(
        h, wt, b2, counts, lists, base, wl, out, cap);
  } else {
    unsigned short* h = (unsigned short*)(ws + OFF_XB);
    long cap_rows = ((long)ws_size - (long)OFF_XB) / (DF * 2);
    if (cap_rows >= 24576) {
      int cap = (int)(cap_rows > 65536 ? 65536 : cap_rows);
      prefix_kernel<<<1, 64, 0, stream>>>(counts, base);
      ffn1_kernel<<<dim3(DF / 128, NT / 128, NEXP), 256, 0, stream>>>(
          x, w1, b1, counts, lists, base, h, cap, -1);
      ffn2_kernel<<<dim3(DM / 128, NT / 128, NEXP), 256, 0, stream>>>(
          h, w2, b2, counts, lists, base, wl, out, cap, -1);
    } else {
      hipMemsetAsync(base, 0, 64, stream);
      for (int e = 0; e < NEXP; ++e) {
        ffn1_kernel<<<dim3(DF / 128, NT / 128, 1), 256, 0, stream>>>(
            x, w1, b1, counts, lists, base, h, NT, e);
        ffn2_kernel<<<dim3(DM / 128, NT / 128, 1), 256, 0, stream>>>(
            h, w2, b2, counts, lists, base, wl, out, NT, e);
      }
    }
  }
}